// Round 1
// baseline (919.278 us; speedup 1.0000x reference)
//
#include <hip/hip_runtime.h>
#include <hip/hip_bf16.h>
#include <math.h>

// Problem constants (from reference)
#define NN 100000      // nodes
#define NP 3           // metapaths
#define NE 800000      // edges per path
#define NH 4           // heads
#define ND 32          // dim per head
#define HD 128         // H*D
#define NHID 64        // semantic hidden
#define CAP 48         // per-node in-edge cap (Poisson(8): P(deg>=48) ~ 1e-25)

// ---------------- feature GEMM: feat = h @ W_p  ([NN,128]@[128,128]) ----------------
// block 256, C-tile 64x128, micro 4 rows x 8 cols (col pairs strided 32, conflict-free LDS)
__global__ __launch_bounds__(256) void gemm_feat_kernel(
    const float* __restrict__ h, const float* __restrict__ Wp, float* __restrict__ feat) {
  __shared__ float hs[64][33];   // +1 pad breaks 16-way row-stride conflict
  __shared__ float Ws[32][128];
  const int t = threadIdx.x;
  const int rowBase = blockIdx.x * 64;
  const int rg = t >> 4, cg = t & 15;
  const int r0 = rg * 4;
  float acc[4][8];
#pragma unroll
  for (int i = 0; i < 4; ++i)
#pragma unroll
    for (int j = 0; j < 8; ++j) acc[i][j] = 0.f;

  for (int k0 = 0; k0 < 128; k0 += 32) {
    // stage h tile: 64x32 floats = 512 float4
#pragma unroll
    for (int i = 0; i < 2; ++i) {
      int idx = t + i * 256;
      int rr = idx >> 3, cc = (idx & 7) * 4;
      int grow = rowBase + rr;
      float4 v = make_float4(0.f, 0.f, 0.f, 0.f);
      if (grow < NN) v = *(const float4*)(h + (size_t)grow * 128 + k0 + cc);
      hs[rr][cc + 0] = v.x; hs[rr][cc + 1] = v.y; hs[rr][cc + 2] = v.z; hs[rr][cc + 3] = v.w;
    }
    // stage W tile: 32x128 floats = 1024 float4
#pragma unroll
    for (int i = 0; i < 4; ++i) {
      int idx = t + i * 256;
      int rr = idx >> 5, cc = (idx & 31) * 4;
      *(float4*)&Ws[rr][cc] = *(const float4*)(Wp + (size_t)(k0 + rr) * 128 + cc);
    }
    __syncthreads();
#pragma unroll
    for (int kk = 0; kk < 32; ++kk) {
      float a0 = hs[r0 + 0][kk], a1 = hs[r0 + 1][kk], a2 = hs[r0 + 2][kk], a3 = hs[r0 + 3][kk];
#pragma unroll
      for (int j = 0; j < 4; ++j) {
        float2 w = *(const float2*)&Ws[kk][2 * cg + 32 * j];
        acc[0][2 * j] += a0 * w.x; acc[0][2 * j + 1] += a0 * w.y;
        acc[1][2 * j] += a1 * w.x; acc[1][2 * j + 1] += a1 * w.y;
        acc[2][2 * j] += a2 * w.x; acc[2][2 * j + 1] += a2 * w.y;
        acc[3][2 * j] += a3 * w.x; acc[3][2 * j + 1] += a3 * w.y;
      }
    }
    __syncthreads();
  }
#pragma unroll
  for (int i = 0; i < 4; ++i) {
    int grow = rowBase + r0 + i;
    if (grow >= NN) continue;
#pragma unroll
    for (int j = 0; j < 4; ++j) {
      float2 w; w.x = acc[i][2 * j]; w.y = acc[i][2 * j + 1];
      *(float2*)(feat + (size_t)grow * 128 + 2 * cg + 32 * j) = w;
    }
  }
}

// ---------------- el/er: per-(node,head) attention dots ----------------
__global__ __launch_bounds__(256) void eler_kernel(
    const float* __restrict__ feat, const float* __restrict__ al, const float* __restrict__ ar,
    float* __restrict__ el, float* __restrict__ er) {
  int t = blockIdx.x * blockDim.x + threadIdx.x;
  if (t >= NN * NH) return;
  int n = t >> 2, hh = t & 3;
  const float* f = feat + (size_t)n * 128 + hh * 32;
  const float* a = al + hh * 32;
  const float* b = ar + hh * 32;
  float sl = 0.f, sr = 0.f;
#pragma unroll
  for (int d4 = 0; d4 < 32; d4 += 4) {
    float4 fv = *(const float4*)(f + d4);
    float4 av = *(const float4*)(a + d4);
    float4 bv = *(const float4*)(b + d4);
    sl += fv.x * av.x + fv.y * av.y + fv.z * av.z + fv.w * av.w;
    sr += fv.x * bv.x + fv.y * bv.y + fv.z * bv.z + fv.w * bv.w;
  }
  el[t] = sl; er[t] = sr;
}

// ---------------- bucket fill: capped per-dst in-edge lists ----------------
__global__ __launch_bounds__(256) void fill_kernel(
    const int* __restrict__ src, const int* __restrict__ dst,
    int* __restrict__ cnt, int* __restrict__ elist) {
  int e = blockIdx.x * blockDim.x + threadIdx.x;
  if (e >= NE) return;
  int d = dst[e];
  int pos = atomicAdd(&cnt[d], 1);
  if (pos < CAP) elist[(size_t)d * CAP + pos] = src[e];
}

// ---------------- gather: one wave per dst node; softmax + weighted sum ----------------
__global__ __launch_bounds__(256) void gather_kernel(
    const float* __restrict__ feat, const float* __restrict__ el,
    const float* __restrict__ er, const int* __restrict__ cnt,
    const int* __restrict__ elist, const float* __restrict__ bias,
    float* __restrict__ zout) {
  int wid = threadIdx.x >> 6;
  int lane = threadIdx.x & 63;
  int n = blockIdx.x * 4 + wid;
  if (n >= NN) return;
  int deg = cnt[n]; if (deg > CAP) deg = CAP;
  int myh = lane >> 4;  // lane covers elements 2*lane, 2*lane+1 -> head = lane/16
  float4 ern = *(const float4*)(er + (size_t)n * 4);

  // pass 1: softmax denominator (no max-subtraction: |logit| < ~2, fp32-exact)
  float d0 = 0.f, d1 = 0.f, d2 = 0.f, d3 = 0.f;
  for (int j = lane; j < deg; j += 64) {
    int s = elist[(size_t)n * CAP + j];
    float4 ev = *(const float4*)(el + (size_t)s * 4);
    float e0 = ev.x + ern.x; e0 = e0 > 0.f ? e0 : 0.2f * e0; d0 += __expf(e0);
    float e1 = ev.y + ern.y; e1 = e1 > 0.f ? e1 : 0.2f * e1; d1 += __expf(e1);
    float e2 = ev.z + ern.z; e2 = e2 > 0.f ? e2 : 0.2f * e2; d2 += __expf(e2);
    float e3 = ev.w + ern.w; e3 = e3 > 0.f ? e3 : 0.2f * e3; d3 += __expf(e3);
  }
#pragma unroll
  for (int m = 32; m >= 1; m >>= 1) {
    d0 += __shfl_xor(d0, m, 64);
    d1 += __shfl_xor(d1, m, 64);
    d2 += __shfl_xor(d2, m, 64);
    d3 += __shfl_xor(d3, m, 64);
  }
  float dm = myh == 0 ? d0 : (myh == 1 ? d1 : (myh == 2 ? d2 : d3));
  float erm = myh == 0 ? ern.x : (myh == 1 ? ern.y : (myh == 2 ? ern.z : ern.w));
  float rden = dm > 0.f ? 1.f / dm : 0.f;

  // pass 2: alpha-weighted gather of feat rows (512B coalesced per wave)
  float a0 = 0.f, a1 = 0.f;
  for (int j = 0; j < deg; ++j) {
    int s = elist[(size_t)n * CAP + j];            // wave-uniform
    float ee = el[(size_t)s * 4 + myh] + erm;
    ee = ee > 0.f ? ee : 0.2f * ee;
    float alpha = __expf(ee) * rden;
    float2 f = *(const float2*)(feat + (size_t)s * 128 + 2 * lane);
    a0 += alpha * f.x; a1 += alpha * f.y;
  }
  float2 b = *(const float2*)(bias + 2 * lane);
  float2 o; o.x = a0 + b.x; o.y = a1 + b.y;
  *(float2*)(zout + (size_t)n * (NP * 128) + 2 * lane) = o;
}

// ---------------- semantic attention scores: s[p] = sum_n tanh(z_np @ W1 + b1) @ w2 ----------------
// block 256, tile 128 rows x 64 cols, micro 8x4
__global__ __launch_bounds__(256) void sem_kernel(
    const float* __restrict__ z, const float* __restrict__ W1,
    const float* __restrict__ b1, const float* __restrict__ w2,
    float* __restrict__ s) {
  __shared__ float as[128][33];
  __shared__ float Bs[32][64];
  __shared__ float red[256];
  const int p = blockIdx.y;
  const float* A = z + p * 128;   // row stride NP*128
  const int t = threadIdx.x;
  const int rowBase = blockIdx.x * 128;
  const int rg = t >> 4, cg = t & 15;
  const int r0 = rg * 8;
  float acc[8][4];
#pragma unroll
  for (int i = 0; i < 8; ++i)
#pragma unroll
    for (int j = 0; j < 4; ++j) acc[i][j] = 0.f;

  for (int k0 = 0; k0 < 128; k0 += 32) {
    // stage A tile: 128x32 = 1024 float4
#pragma unroll
    for (int i = 0; i < 4; ++i) {
      int idx = t + i * 256;
      int rr = idx >> 3, cc = (idx & 7) * 4;
      int grow = rowBase + rr;
      float4 v = make_float4(0.f, 0.f, 0.f, 0.f);
      if (grow < NN) v = *(const float4*)(A + (size_t)grow * (NP * 128) + k0 + cc);
      as[rr][cc + 0] = v.x; as[rr][cc + 1] = v.y; as[rr][cc + 2] = v.z; as[rr][cc + 3] = v.w;
    }
    // stage B tile: 32x64 = 512 float4
#pragma unroll
    for (int i = 0; i < 2; ++i) {
      int idx = t + i * 256;
      int rr = idx >> 4, cc = (idx & 15) * 4;
      *(float4*)&Bs[rr][cc] = *(const float4*)(W1 + (size_t)(k0 + rr) * 64 + cc);
    }
    __syncthreads();
#pragma unroll
    for (int kk = 0; kk < 32; ++kk) {
      float a[8];
#pragma unroll
      for (int i = 0; i < 8; ++i) a[i] = as[r0 + i][kk];
#pragma unroll
      for (int j = 0; j < 2; ++j) {
        float2 w = *(const float2*)&Bs[kk][2 * cg + 32 * j];
#pragma unroll
        for (int i = 0; i < 8; ++i) {
          acc[i][2 * j] += a[i] * w.x;
          acc[i][2 * j + 1] += a[i] * w.y;
        }
      }
    }
    __syncthreads();
  }
  // epilogue: tanh + dot with w2, reduce to scalar
  int c[4] = {2 * cg, 2 * cg + 1, 2 * cg + 32, 2 * cg + 33};
  float b1v[4], w2v[4];
#pragma unroll
  for (int j = 0; j < 4; ++j) { b1v[j] = b1[c[j]]; w2v[j] = w2[c[j]]; }
  float partial = 0.f;
#pragma unroll
  for (int i = 0; i < 8; ++i) {
    if (rowBase + r0 + i < NN) {
#pragma unroll
      for (int j = 0; j < 4; ++j) partial += tanhf(acc[i][j] + b1v[j]) * w2v[j];
    }
  }
  red[t] = partial;
  __syncthreads();
  for (int st = 128; st >= 1; st >>= 1) {
    if (t < st) red[t] += red[t + st];
    __syncthreads();
  }
  if (t == 0) atomicAdd(&s[p], red[0]);
}

// ---------------- beta = softmax(s / N) ----------------
__global__ void beta_kernel(const float* __restrict__ s, float* __restrict__ beta) {
  if (threadIdx.x == 0 && blockIdx.x == 0) {
    float w0 = s[0] / (float)NN, w1 = s[1] / (float)NN, w2 = s[2] / (float)NN;
    float m = fmaxf(w0, fmaxf(w1, w2));
    float e0 = __expf(w0 - m), e1 = __expf(w1 - m), e2 = __expf(w2 - m);
    float inv = 1.f / (e0 + e1 + e2);
    beta[0] = e0 * inv; beta[1] = e1 * inv; beta[2] = e2 * inv;
  }
}

// ---------------- final combine: out = sum_p beta[p] * z[:,p,:] ----------------
__global__ __launch_bounds__(256) void final_kernel(
    const float* __restrict__ z, const float* __restrict__ beta, float* __restrict__ out) {
  int i = blockIdx.x * blockDim.x + threadIdx.x;  // over NN*32 float4
  if (i >= NN * 32) return;
  int n = i >> 5, c4 = i & 31;
  float b0 = beta[0], b1 = beta[1], b2 = beta[2];
  const float* zr = z + (size_t)n * (NP * 128);
  float4 v0 = *((const float4*)zr + c4);
  float4 v1 = *((const float4*)(zr + 128) + c4);
  float4 v2 = *((const float4*)(zr + 256) + c4);
  float4 o;
  o.x = b0 * v0.x + b1 * v1.x + b2 * v2.x;
  o.y = b0 * v0.y + b1 * v1.y + b2 * v2.y;
  o.z = b0 * v0.z + b1 * v1.z + b2 * v2.z;
  o.w = b0 * v0.w + b1 * v1.w + b2 * v2.w;
  ((float4*)out)[i] = o;
}

// ---------------- init: zero counters + score accumulators ----------------
__global__ __launch_bounds__(256) void zero_kernel(int* __restrict__ cnt, float* __restrict__ s) {
  int i = blockIdx.x * blockDim.x + threadIdx.x;
  if (i < NP * NN) cnt[i] = 0;
  if (i < NP) s[i] = 0.f;
}

extern "C" void kernel_launch(void* const* d_in, const int* in_sizes, int n_in,
                              void* d_out, int out_size, void* d_ws, size_t ws_size,
                              hipStream_t stream) {
  const float* h    = (const float*)d_in[0];
  const int*   esrc = (const int*)d_in[1];
  const int*   edst = (const int*)d_in[2];
  const float* W    = (const float*)d_in[3];
  const float* al   = (const float*)d_in[4];
  const float* ar   = (const float*)d_in[5];
  const float* bias = (const float*)d_in[6];
  const float* w1   = (const float*)d_in[7];
  const float* b1   = (const float*)d_in[8];
  const float* w2   = (const float*)d_in[9];
  float* out = (float*)d_out;

  // workspace layout (floats), all 16B-aligned; total ~218 MiB
  float* ws   = (float*)d_ws;
  float* z    = ws;                       // NN*NP*128 = 38,400,000
  float* feat = z + (size_t)NN * NP * 128; // 12,800,000
  float* el   = feat + (size_t)NN * 128;   // 400,000
  float* er   = el + (size_t)NN * NH;      // 400,000
  float* s    = er + (size_t)NN * NH;      // 16 (padded)
  float* beta = s + 16;                    // 16 (padded)
  int*   cnt  = (int*)(beta + 16);         // NP*NN = 300,000
  int*   elist = cnt + (size_t)NP * NN;    // NN*CAP = 4,800,000 (shared across paths)

  zero_kernel<<<(NP * NN + 255) / 256, 256, 0, stream>>>(cnt, s);

  for (int p = 0; p < NP; ++p) {
    gemm_feat_kernel<<<(NN + 63) / 64, 256, 0, stream>>>(h, W + (size_t)p * 128 * 128, feat);
    eler_kernel<<<(NN * NH + 255) / 256, 256, 0, stream>>>(feat, al + p * 128, ar + p * 128, el, er);
    fill_kernel<<<(NE + 255) / 256, 256, 0, stream>>>(esrc + (size_t)p * NE, edst + (size_t)p * NE,
                                                      cnt + (size_t)p * NN, elist);
    gather_kernel<<<(NN + 3) / 4, 256, 0, stream>>>(feat, el, er, cnt + (size_t)p * NN, elist,
                                                    bias + p * 128, z + p * 128);
  }

  dim3 semGrid((NN + 127) / 128, NP);
  sem_kernel<<<semGrid, 256, 0, stream>>>(z, w1, b1, w2, s);
  beta_kernel<<<1, 64, 0, stream>>>(s, beta);
  final_kernel<<<(NN * 32 + 255) / 256, 256, 0, stream>>>(z, beta, out);
}

// Round 2
// 699.916 us; speedup vs baseline: 1.3134x; 1.3134x over previous
//
#include <hip/hip_runtime.h>
#include <hip/hip_bf16.h>
#include <math.h>

// Problem constants (from reference)
#define NN 100000      // nodes
#define NP 3           // metapaths
#define NE 800000      // edges per path
#define NH 4           // heads
#define ND 32          // dim per head
#define HD 128         // H*D
#define NHID 64        // semantic hidden
#define CAP 48         // per-node in-edge cap (Poisson(8): P(deg>=48) ~ 1e-25)

__device__ __forceinline__ unsigned short f2bf(float f) {
  union { float f; unsigned int u; } v; v.f = f;
  unsigned int r = v.u + 0x7FFFu + ((v.u >> 16) & 1u);   // round-to-nearest-even
  return (unsigned short)(r >> 16);
}
__device__ __forceinline__ float bf2f(unsigned short u) {
  return __uint_as_float(((unsigned int)u) << 16);
}

// ---------------- fused GEMM + el/er: feat_bf16 = bf16(h @ W_p), el/er in epilogue ----------
// block 256, C-tile 64x128, micro 4 rows x 8 cols (cols 4cg..4cg+3 and 64+4cg..+3)
// A tile stored transposed in LDS -> all compute reads are ds_read_b128.
__global__ __launch_bounds__(256) void gemm_feat_eler_kernel(
    const float* __restrict__ h, const float* __restrict__ Wp,
    const float* __restrict__ al, const float* __restrict__ ar,
    unsigned short* __restrict__ featb, float* __restrict__ el, float* __restrict__ er) {
  __shared__ float hs[32][66];    // [kk][row], 66 stride breaks write conflicts
  __shared__ float Ws[32][128];
  const int t = threadIdx.x;
  const int rowBase = blockIdx.x * 64;
  const int rg = t >> 4, cg = t & 15;
  const int r0 = rg * 4;
  float acc[4][8];
#pragma unroll
  for (int i = 0; i < 4; ++i)
#pragma unroll
    for (int j = 0; j < 8; ++j) acc[i][j] = 0.f;

  for (int k0 = 0; k0 < 128; k0 += 32) {
    // stage h tile 64x32 (transposed into hs[kk][row]): 512 float4 loads
#pragma unroll
    for (int i = 0; i < 2; ++i) {
      int idx = t + i * 256;
      int rr = idx >> 3, cc = (idx & 7) * 4;
      int grow = rowBase + rr;
      float4 v = make_float4(0.f, 0.f, 0.f, 0.f);
      if (grow < NN) v = *(const float4*)(h + (size_t)grow * 128 + k0 + cc);
      hs[cc + 0][rr] = v.x; hs[cc + 1][rr] = v.y; hs[cc + 2][rr] = v.z; hs[cc + 3][rr] = v.w;
    }
    // stage W tile 32x128: 1024 float4
#pragma unroll
    for (int i = 0; i < 4; ++i) {
      int idx = t + i * 256;
      int rr = idx >> 5, cc = (idx & 31) * 4;
      *(float4*)&Ws[rr][cc] = *(const float4*)(Wp + (size_t)(k0 + rr) * 128 + cc);
    }
    __syncthreads();
#pragma unroll
    for (int kk = 0; kk < 32; ++kk) {
      float4 a  = *(const float4*)&hs[kk][r0];
      float4 b0 = *(const float4*)&Ws[kk][4 * cg];
      float4 b1 = *(const float4*)&Ws[kk][64 + 4 * cg];
      const float av[4] = {a.x, a.y, a.z, a.w};
#pragma unroll
      for (int i = 0; i < 4; ++i) {
        acc[i][0] += av[i] * b0.x; acc[i][1] += av[i] * b0.y;
        acc[i][2] += av[i] * b0.z; acc[i][3] += av[i] * b0.w;
        acc[i][4] += av[i] * b1.x; acc[i][5] += av[i] * b1.y;
        acc[i][6] += av[i] * b1.z; acc[i][7] += av[i] * b1.w;
      }
    }
    __syncthreads();
  }

  // attention vectors for my 8 cols
  float4 al0 = *(const float4*)(al + 4 * cg);
  float4 al1 = *(const float4*)(al + 64 + 4 * cg);
  float4 ar0 = *(const float4*)(ar + 4 * cg);
  float4 ar1 = *(const float4*)(ar + 64 + 4 * cg);

#pragma unroll
  for (int i = 0; i < 4; ++i) {
    int grow = rowBase + r0 + i;
    // partial attention dots (cols 4cg..+3 -> head cg>=8; cols 64+4cg..+3 -> head 2+(cg>=8))
    float pl0 = acc[i][0] * al0.x + acc[i][1] * al0.y + acc[i][2] * al0.z + acc[i][3] * al0.w;
    float pl1 = acc[i][4] * al1.x + acc[i][5] * al1.y + acc[i][6] * al1.z + acc[i][7] * al1.w;
    float pr0 = acc[i][0] * ar0.x + acc[i][1] * ar0.y + acc[i][2] * ar0.z + acc[i][3] * ar0.w;
    float pr1 = acc[i][4] * ar1.x + acc[i][5] * ar1.y + acc[i][6] * ar1.z + acc[i][7] * ar1.w;
#pragma unroll
    for (int m = 1; m <= 4; m <<= 1) {
      pl0 += __shfl_xor(pl0, m); pl1 += __shfl_xor(pl1, m);
      pr0 += __shfl_xor(pr0, m); pr1 += __shfl_xor(pr1, m);
    }
    if (grow < NN) {
      if ((cg & 7) == 0) {
        int hb = cg >> 3;   // 0 or 1
        el[grow * 4 + hb] = pl0; el[grow * 4 + 2 + hb] = pl1;
        er[grow * 4 + hb] = pr0; er[grow * 4 + 2 + hb] = pr1;
      }
      ushort4 o0, o1;
      o0.x = f2bf(acc[i][0]); o0.y = f2bf(acc[i][1]); o0.z = f2bf(acc[i][2]); o0.w = f2bf(acc[i][3]);
      o1.x = f2bf(acc[i][4]); o1.y = f2bf(acc[i][5]); o1.z = f2bf(acc[i][6]); o1.w = f2bf(acc[i][7]);
      *(ushort4*)(featb + (size_t)grow * 128 + 4 * cg) = o0;
      *(ushort4*)(featb + (size_t)grow * 128 + 64 + 4 * cg) = o1;
    }
  }
}

// ---------------- bucket fill: capped per-dst in-edge lists ----------------
__global__ __launch_bounds__(256) void fill_kernel(
    const int* __restrict__ src, const int* __restrict__ dst,
    int* __restrict__ cnt, int* __restrict__ elist) {
  int e = blockIdx.x * blockDim.x + threadIdx.x;
  if (e >= NE) return;
  int d = dst[e];
  int pos = atomicAdd(&cnt[d], 1);
  if (pos < CAP) elist[(size_t)d * CAP + pos] = src[e];
}

// ---------------- gather: one wave per dst node; softmax + bf16-weighted sum ----------------
__global__ __launch_bounds__(256) void gather_kernel(
    const unsigned short* __restrict__ featb, const float* __restrict__ el,
    const float* __restrict__ er, const int* __restrict__ cnt,
    const int* __restrict__ elist, const float* __restrict__ bias,
    float* __restrict__ zout) {
  __shared__ int   s_src[4][CAP];
  __shared__ float s_alf[4][4 * CAP];   // [wave][head*CAP + j]
  const int wid = threadIdx.x >> 6;
  const int lane = threadIdx.x & 63;
  const int n = blockIdx.x * 4 + wid;        // NN % 4 == 0, no guard
  int deg = cnt[n]; deg = deg > CAP ? CAP : deg;
  float4 ern = *(const float4*)(er + (size_t)n * 4);

  // pass 1: lane j handles edge j (deg <= 48 < 64). No max-subtraction: |logit|<~2.
  float x0 = 0.f, x1 = 0.f, x2 = 0.f, x3 = 0.f;
  int s = 0;
  if (lane < deg) {
    s = elist[(size_t)n * CAP + lane];
    float4 ev = *(const float4*)(el + (size_t)s * 4);
    float e0 = ev.x + ern.x; e0 = e0 > 0.f ? e0 : 0.2f * e0; x0 = __expf(e0);
    float e1 = ev.y + ern.y; e1 = e1 > 0.f ? e1 : 0.2f * e1; x1 = __expf(e1);
    float e2 = ev.z + ern.z; e2 = e2 > 0.f ? e2 : 0.2f * e2; x2 = __expf(e2);
    float e3 = ev.w + ern.w; e3 = e3 > 0.f ? e3 : 0.2f * e3; x3 = __expf(e3);
  }
  float d0 = x0, d1 = x1, d2 = x2, d3 = x3;
#pragma unroll
  for (int m = 1; m <= 32; m <<= 1) {
    d0 += __shfl_xor(d0, m); d1 += __shfl_xor(d1, m);
    d2 += __shfl_xor(d2, m); d3 += __shfl_xor(d3, m);
  }
  float r0 = d0 > 0.f ? 1.f / d0 : 0.f;
  float r1 = d1 > 0.f ? 1.f / d1 : 0.f;
  float r2 = d2 > 0.f ? 1.f / d2 : 0.f;
  float r3 = d3 > 0.f ? 1.f / d3 : 0.f;
  if (lane < CAP) {
    s_src[wid][lane] = s;                        // 0 for lane >= deg
    s_alf[wid][0 * CAP + lane] = x0 * r0;        // 0 for lane >= deg
    s_alf[wid][1 * CAP + lane] = x1 * r1;
    s_alf[wid][2 * CAP + lane] = x2 * r2;
    s_alf[wid][3 * CAP + lane] = x3 * r3;
  }
  __syncthreads();

  // pass 2: 2 edges per iteration (half-wave each, ushort4=8B/lane), unrolled x2.
  const int half = lane >> 5, c = lane & 31;
  const int hh = c >> 3;                         // head of my 4 columns
  const float* alfh = &s_alf[wid][hh * CAP];
  const int* srcs = s_src[wid];
  float a0 = 0.f, a1 = 0.f, a2 = 0.f, a3 = 0.f;
  int deg4 = (deg + 3) & ~3;
  for (int i = 0; i < deg4; i += 4) {
    int jA = i + half, jB = i + 2 + half;
    int sA = srcs[jA], sB = srcs[jB];
    float aA = alfh[jA], aB = alfh[jB];
    ushort4 fA = *(const ushort4*)(featb + (size_t)sA * 128 + 4 * c);
    ushort4 fB = *(const ushort4*)(featb + (size_t)sB * 128 + 4 * c);
    a0 += aA * bf2f(fA.x); a1 += aA * bf2f(fA.y);
    a2 += aA * bf2f(fA.z); a3 += aA * bf2f(fA.w);
    a0 += aB * bf2f(fB.x); a1 += aB * bf2f(fB.y);
    a2 += aB * bf2f(fB.z); a3 += aB * bf2f(fB.w);
  }
  a0 += __shfl_xor(a0, 32); a1 += __shfl_xor(a1, 32);
  a2 += __shfl_xor(a2, 32); a3 += __shfl_xor(a3, 32);
  if (half == 0) {
    float4 b = *(const float4*)(bias + 4 * c);
    float4 o; o.x = a0 + b.x; o.y = a1 + b.y; o.z = a2 + b.z; o.w = a3 + b.w;
    *(float4*)(zout + (size_t)n * (NP * 128) + 4 * c) = o;
  }
}

// ---------------- semantic attention scores: s[p] = sum_n tanh(z_np @ W1 + b1) @ w2 ----------------
__global__ __launch_bounds__(256) void sem_kernel(
    const float* __restrict__ z, const float* __restrict__ W1,
    const float* __restrict__ b1, const float* __restrict__ w2,
    float* __restrict__ s) {
  __shared__ float as[128][33];
  __shared__ float Bs[32][64];
  __shared__ float red[256];
  const int p = blockIdx.y;
  const float* A = z + p * 128;   // row stride NP*128
  const int t = threadIdx.x;
  const int rowBase = blockIdx.x * 128;
  const int rg = t >> 4, cg = t & 15;
  const int r0 = rg * 8;
  float acc[8][4];
#pragma unroll
  for (int i = 0; i < 8; ++i)
#pragma unroll
    for (int j = 0; j < 4; ++j) acc[i][j] = 0.f;

  for (int k0 = 0; k0 < 128; k0 += 32) {
#pragma unroll
    for (int i = 0; i < 4; ++i) {
      int idx = t + i * 256;
      int rr = idx >> 3, cc = (idx & 7) * 4;
      int grow = rowBase + rr;
      float4 v = make_float4(0.f, 0.f, 0.f, 0.f);
      if (grow < NN) v = *(const float4*)(A + (size_t)grow * (NP * 128) + k0 + cc);
      as[rr][cc + 0] = v.x; as[rr][cc + 1] = v.y; as[rr][cc + 2] = v.z; as[rr][cc + 3] = v.w;
    }
#pragma unroll
    for (int i = 0; i < 2; ++i) {
      int idx = t + i * 256;
      int rr = idx >> 4, cc = (idx & 15) * 4;
      *(float4*)&Bs[rr][cc] = *(const float4*)(W1 + (size_t)(k0 + rr) * 64 + cc);
    }
    __syncthreads();
#pragma unroll
    for (int kk = 0; kk < 32; ++kk) {
      float a[8];
#pragma unroll
      for (int i = 0; i < 8; ++i) a[i] = as[r0 + i][kk];
#pragma unroll
      for (int j = 0; j < 2; ++j) {
        float2 w = *(const float2*)&Bs[kk][2 * cg + 32 * j];
#pragma unroll
        for (int i = 0; i < 8; ++i) {
          acc[i][2 * j] += a[i] * w.x;
          acc[i][2 * j + 1] += a[i] * w.y;
        }
      }
    }
    __syncthreads();
  }
  int c[4] = {2 * cg, 2 * cg + 1, 2 * cg + 32, 2 * cg + 33};
  float b1v[4], w2v[4];
#pragma unroll
  for (int j = 0; j < 4; ++j) { b1v[j] = b1[c[j]]; w2v[j] = w2[c[j]]; }
  float partial = 0.f;
#pragma unroll
  for (int i = 0; i < 8; ++i) {
    if (rowBase + r0 + i < NN) {
#pragma unroll
      for (int j = 0; j < 4; ++j) partial += tanhf(acc[i][j] + b1v[j]) * w2v[j];
    }
  }
  red[t] = partial;
  __syncthreads();
  for (int st = 128; st >= 1; st >>= 1) {
    if (t < st) red[t] += red[t + st];
    __syncthreads();
  }
  if (t == 0) atomicAdd(&s[p], red[0]);
}

// ---------------- beta = softmax(s / N) ----------------
__global__ void beta_kernel(const float* __restrict__ s, float* __restrict__ beta) {
  if (threadIdx.x == 0 && blockIdx.x == 0) {
    float w0 = s[0] / (float)NN, w1 = s[1] / (float)NN, w2 = s[2] / (float)NN;
    float m = fmaxf(w0, fmaxf(w1, w2));
    float e0 = __expf(w0 - m), e1 = __expf(w1 - m), e2 = __expf(w2 - m);
    float inv = 1.f / (e0 + e1 + e2);
    beta[0] = e0 * inv; beta[1] = e1 * inv; beta[2] = e2 * inv;
  }
}

// ---------------- final combine: out = sum_p beta[p] * z[:,p,:] ----------------
__global__ __launch_bounds__(256) void final_kernel(
    const float* __restrict__ z, const float* __restrict__ beta, float* __restrict__ out) {
  int i = blockIdx.x * blockDim.x + threadIdx.x;  // over NN*32 float4
  if (i >= NN * 32) return;
  int n = i >> 5, c4 = i & 31;
  float b0 = beta[0], b1 = beta[1], b2 = beta[2];
  const float* zr = z + (size_t)n * (NP * 128);
  float4 v0 = *((const float4*)zr + c4);
  float4 v1 = *((const float4*)(zr + 128) + c4);
  float4 v2 = *((const float4*)(zr + 256) + c4);
  float4 o;
  o.x = b0 * v0.x + b1 * v1.x + b2 * v2.x;
  o.y = b0 * v0.y + b1 * v1.y + b2 * v2.y;
  o.z = b0 * v0.z + b1 * v1.z + b2 * v2.z;
  o.w = b0 * v0.w + b1 * v1.w + b2 * v2.w;
  ((float4*)out)[i] = o;
}

// ---------------- init: zero counters + score accumulators ----------------
__global__ __launch_bounds__(256) void zero_kernel(int* __restrict__ cnt, float* __restrict__ s) {
  int i = blockIdx.x * blockDim.x + threadIdx.x;
  if (i < NP * NN) cnt[i] = 0;
  if (i < NP) s[i] = 0.f;
}

extern "C" void kernel_launch(void* const* d_in, const int* in_sizes, int n_in,
                              void* d_out, int out_size, void* d_ws, size_t ws_size,
                              hipStream_t stream) {
  const float* h    = (const float*)d_in[0];
  const int*   esrc = (const int*)d_in[1];
  const int*   edst = (const int*)d_in[2];
  const float* W    = (const float*)d_in[3];
  const float* al   = (const float*)d_in[4];
  const float* ar   = (const float*)d_in[5];
  const float* bias = (const float*)d_in[6];
  const float* w1   = (const float*)d_in[7];
  const float* b1   = (const float*)d_in[8];
  const float* w2   = (const float*)d_in[9];
  float* out = (float*)d_out;

  // workspace layout (floats), ~203 MiB total
  float* ws   = (float*)d_ws;
  float* z    = ws;                              // NN*NP*128 = 38,400,000 f
  unsigned short* featb = (unsigned short*)(z + (size_t)NN * NP * 128);  // NN*128 bf16 = 6.4M f
  float* el   = (float*)(featb + (size_t)NN * 128);  // NN*4
  float* er   = el + (size_t)NN * NH;            // NN*4
  float* s    = er + (size_t)NN * NH;            // 16 (padded)
  float* beta = s + 16;                          // 16 (padded)
  int*   cnt  = (int*)(beta + 16);               // NP*NN
  int*   elist = cnt + (size_t)NP * NN;          // NN*CAP (shared across paths, sequential)

  zero_kernel<<<(NP * NN + 255) / 256, 256, 0, stream>>>(cnt, s);

  for (int p = 0; p < NP; ++p) {
    gemm_feat_eler_kernel<<<(NN + 63) / 64, 256, 0, stream>>>(
        h, W + (size_t)p * 128 * 128, al + p * 128, ar + p * 128, featb, el, er);
    fill_kernel<<<(NE + 255) / 256, 256, 0, stream>>>(esrc + (size_t)p * NE, edst + (size_t)p * NE,
                                                      cnt + (size_t)p * NN, elist);
    gather_kernel<<<NN / 4, 256, 0, stream>>>(featb, el, er, cnt + (size_t)p * NN, elist,
                                              bias + p * 128, z + p * 128);
  }

  dim3 semGrid((NN + 127) / 128, NP);
  sem_kernel<<<semGrid, 256, 0, stream>>>(z, w1, b1, w2, s);
  beta_kernel<<<1, 64, 0, stream>>>(s, beta);
  final_kernel<<<(NN * 32 + 255) / 256, 256, 0, stream>>>(z, beta, out);
}

// Round 3
// 621.756 us; speedup vs baseline: 1.4785x; 1.1257x over previous
//
#include <hip/hip_runtime.h>
#include <hip/hip_bf16.h>
#include <math.h>

// Problem constants (from reference)
#define NN 100000      // nodes
#define NP 3           // metapaths
#define NE 800000      // edges per path
#define NH 4           // heads
#define ND 32          // dim per head
#define HD 128         // H*D
#define NHID 64        // semantic hidden
#define CAP 48         // per-node in-edge cap (Poisson(8): P(deg>=48) ~ 1e-25)

typedef __attribute__((ext_vector_type(8))) short short8;
typedef __attribute__((ext_vector_type(4))) float f32x4;

__device__ __forceinline__ unsigned short f2bf(float f) {
  union { float f; unsigned int u; } v; v.f = f;
  unsigned int r = v.u + 0x7FFFu + ((v.u >> 16) & 1u);   // round-to-nearest-even
  return (unsigned short)(r >> 16);
}
__device__ __forceinline__ float bf2f(unsigned short u) {
  return __uint_as_float(((unsigned int)u) << 16);
}
__device__ __forceinline__ float tanh_fast(float x) {
  // tanh(x) = 1 - 2/(1+e^{2x}); saturates correctly for large |x|
  return 1.f - 2.f / (1.f + __expf(2.f * x));
}

// ---------------- cast h (fp32 -> bf16), once per launch ----------------
__global__ __launch_bounds__(256) void cast_h_kernel(
    const float* __restrict__ h, unsigned short* __restrict__ hb) {
  int i = blockIdx.x * blockDim.x + threadIdx.x;   // NN*32 threads, 4 elems each
  if (i >= NN * 32) return;
  float4 v = ((const float4*)h)[i];
  ushort4 o;
  o.x = f2bf(v.x); o.y = f2bf(v.y); o.z = f2bf(v.z); o.w = f2bf(v.w);
  ((ushort4*)hb)[i] = o;
}

// ---------------- prep weights: transpose + cast W (3x128x128) and sa_w1 (128x64) ----------------
__global__ __launch_bounds__(256) void prep_w_kernel(
    const float* __restrict__ W, const float* __restrict__ W1,
    unsigned short* __restrict__ WT, unsigned short* __restrict__ W1T) {
  int t = blockIdx.x * blockDim.x + threadIdx.x;
  if (t < NP * 128 * 128) {               // WT[p][n][k] = W[p][k][n]
    int p = t >> 14, r = t & 16383, n = r >> 7, k = r & 127;
    WT[t] = f2bf(W[(size_t)p * 16384 + k * 128 + n]);
  } else if (t < NP * 128 * 128 + NHID * 128) {   // W1T[n][k] = W1[k][n]
    int r = t - NP * 128 * 128, n = r >> 7, k = r & 127;
    W1T[r] = f2bf(W1[(size_t)k * NHID + n]);
  }
}

// ---------------- MFMA feature GEMM + fused el/er ----------------
// one wave per 16-row tile; C = 16 rows x 128 cols (8 col-tiles of 16x16), K=128 in 4 chunks.
// A-frag: lane holds hb[row=tile*16+(lane&15)][kc*32 + (lane>>4)*8 .. +7] (16B contiguous).
// B-frag: lane holds WT[n=t*16+(lane&15)][kc*32 + (lane>>4)*8 .. +7].
// C/D: col=lane&15, row=(lane>>4)*4+reg  [m89-verified mapping]
__global__ __launch_bounds__(256) void gemm_feat_mfma_kernel(
    const unsigned short* __restrict__ hb, const unsigned short* __restrict__ WT,
    const float* __restrict__ al, const float* __restrict__ ar,
    unsigned short* __restrict__ featb, float* __restrict__ el, float* __restrict__ er) {
  const int wid = threadIdx.x >> 6, lane = threadIdx.x & 63;
  const int tile = blockIdx.x * 4 + wid;
  if (tile >= NN / 16) return;
  const int c = lane & 15, q = lane >> 4;
  f32x4 acc[8];
#pragma unroll
  for (int t = 0; t < 8; ++t) acc[t] = (f32x4){0.f, 0.f, 0.f, 0.f};

  const unsigned short* arow = hb + (size_t)(tile * 16 + c) * 128 + q * 8;
  const unsigned short* brow = WT + (size_t)c * 128 + q * 8;
#pragma unroll
  for (int kc = 0; kc < 4; ++kc) {
    short8 a = *(const short8*)(arow + kc * 32);
#pragma unroll
    for (int t = 0; t < 8; ++t) {
      short8 b = *(const short8*)(brow + (size_t)t * 16 * 128 + kc * 32);
      acc[t] = __builtin_amdgcn_mfma_f32_16x16x32_bf16(a, b, acc[t], 0, 0, 0);
    }
  }

  // store feat bf16: lane's value (t,i) -> row tile*16+q*4+i, col t*16+c
#pragma unroll
  for (int t = 0; t < 8; ++t)
#pragma unroll
    for (int i = 0; i < 4; ++i)
      featb[(size_t)(tile * 16 + q * 4 + i) * 128 + t * 16 + c] = f2bf(acc[t][i]);

  // fused el/er: head hh covers col-tiles 2hh, 2hh+1
  float alv[8], arv[8];
#pragma unroll
  for (int t = 0; t < 8; ++t) { alv[t] = al[t * 16 + c]; arv[t] = ar[t * 16 + c]; }
  float elp[4][4], erp[4][4];   // [i][hh]
#pragma unroll
  for (int i = 0; i < 4; ++i)
#pragma unroll
    for (int hh = 0; hh < 4; ++hh) {
      elp[i][hh] = acc[2 * hh][i] * alv[2 * hh] + acc[2 * hh + 1][i] * alv[2 * hh + 1];
      erp[i][hh] = acc[2 * hh][i] * arv[2 * hh] + acc[2 * hh + 1][i] * arv[2 * hh + 1];
    }
#pragma unroll
  for (int m = 1; m <= 8; m <<= 1)
#pragma unroll
    for (int i = 0; i < 4; ++i)
#pragma unroll
      for (int hh = 0; hh < 4; ++hh) {
        elp[i][hh] += __shfl_xor(elp[i][hh], m);
        erp[i][hh] += __shfl_xor(erp[i][hh], m);
      }
  if (c == 0) {
#pragma unroll
    for (int i = 0; i < 4; ++i) {
      int row = tile * 16 + q * 4 + i;
      *(float4*)(el + (size_t)row * 4) = make_float4(elp[i][0], elp[i][1], elp[i][2], elp[i][3]);
      *(float4*)(er + (size_t)row * 4) = make_float4(erp[i][0], erp[i][1], erp[i][2], erp[i][3]);
    }
  }
}

// ---------------- bucket fill: capped per-dst in-edge lists ----------------
__global__ __launch_bounds__(256) void fill_kernel(
    const int* __restrict__ src, const int* __restrict__ dst,
    int* __restrict__ cnt, int* __restrict__ elist) {
  int e = blockIdx.x * blockDim.x + threadIdx.x;
  if (e >= NE) return;
  int d = dst[e];
  int pos = atomicAdd(&cnt[d], 1);
  if (pos < CAP) elist[(size_t)d * CAP + pos] = src[e];
}

// ---------------- gather: one wave per dst node; softmax + bf16-weighted sum; bf16 z out ----
__global__ __launch_bounds__(256) void gather_kernel(
    const unsigned short* __restrict__ featb, const float* __restrict__ el,
    const float* __restrict__ er, const int* __restrict__ cnt,
    const int* __restrict__ elist, const float* __restrict__ bias,
    unsigned short* __restrict__ zoutb) {
  __shared__ int   s_src[4][CAP];
  __shared__ float s_alf[4][4 * CAP];   // [wave][head*CAP + j]
  const int wid = threadIdx.x >> 6;
  const int lane = threadIdx.x & 63;
  const int n = blockIdx.x * 4 + wid;        // NN % 4 == 0, no guard
  int deg = cnt[n]; deg = deg > CAP ? CAP : deg;
  float4 ern = *(const float4*)(er + (size_t)n * 4);

  // pass 1: lane j handles edge j (deg <= 48 < 64). No max-subtraction: |logit|<~2.
  float x0 = 0.f, x1 = 0.f, x2 = 0.f, x3 = 0.f;
  int s = 0;
  if (lane < deg) {
    s = elist[(size_t)n * CAP + lane];
    float4 ev = *(const float4*)(el + (size_t)s * 4);
    float e0 = ev.x + ern.x; e0 = e0 > 0.f ? e0 : 0.2f * e0; x0 = __expf(e0);
    float e1 = ev.y + ern.y; e1 = e1 > 0.f ? e1 : 0.2f * e1; x1 = __expf(e1);
    float e2 = ev.z + ern.z; e2 = e2 > 0.f ? e2 : 0.2f * e2; x2 = __expf(e2);
    float e3 = ev.w + ern.w; e3 = e3 > 0.f ? e3 : 0.2f * e3; x3 = __expf(e3);
  }
  float d0 = x0, d1 = x1, d2 = x2, d3 = x3;
#pragma unroll
  for (int m = 1; m <= 32; m <<= 1) {
    d0 += __shfl_xor(d0, m); d1 += __shfl_xor(d1, m);
    d2 += __shfl_xor(d2, m); d3 += __shfl_xor(d3, m);
  }
  float r0 = d0 > 0.f ? 1.f / d0 : 0.f;
  float r1 = d1 > 0.f ? 1.f / d1 : 0.f;
  float r2 = d2 > 0.f ? 1.f / d2 : 0.f;
  float r3 = d3 > 0.f ? 1.f / d3 : 0.f;
  if (lane < CAP) {
    s_src[wid][lane] = s;                        // 0 for lane >= deg
    s_alf[wid][0 * CAP + lane] = x0 * r0;        // 0 for lane >= deg
    s_alf[wid][1 * CAP + lane] = x1 * r1;
    s_alf[wid][2 * CAP + lane] = x2 * r2;
    s_alf[wid][3 * CAP + lane] = x3 * r3;
  }
  __syncthreads();

  // pass 2: 2 edges per iteration (half-wave each, ushort4=8B/lane), unrolled x2.
  const int half = lane >> 5, c = lane & 31;
  const int hh = c >> 3;                         // head of my 4 columns
  const float* alfh = &s_alf[wid][hh * CAP];
  const int* srcs = s_src[wid];
  float a0 = 0.f, a1 = 0.f, a2 = 0.f, a3 = 0.f;
  int deg4 = (deg + 3) & ~3;
  for (int i = 0; i < deg4; i += 4) {
    int jA = i + half, jB = i + 2 + half;
    int sA = srcs[jA], sB = srcs[jB];
    float aA = alfh[jA], aB = alfh[jB];
    ushort4 fA = *(const ushort4*)(featb + (size_t)sA * 128 + 4 * c);
    ushort4 fB = *(const ushort4*)(featb + (size_t)sB * 128 + 4 * c);
    a0 += aA * bf2f(fA.x); a1 += aA * bf2f(fA.y);
    a2 += aA * bf2f(fA.z); a3 += aA * bf2f(fA.w);
    a0 += aB * bf2f(fB.x); a1 += aB * bf2f(fB.y);
    a2 += aB * bf2f(fB.z); a3 += aB * bf2f(fB.w);
  }
  a0 += __shfl_xor(a0, 32); a1 += __shfl_xor(a1, 32);
  a2 += __shfl_xor(a2, 32); a3 += __shfl_xor(a3, 32);
  if (half == 0) {
    float4 b = *(const float4*)(bias + 4 * c);
    ushort4 o;
    o.x = f2bf(a0 + b.x); o.y = f2bf(a1 + b.y);
    o.z = f2bf(a2 + b.z); o.w = f2bf(a3 + b.w);
    *(ushort4*)(zoutb + (size_t)n * (NP * 128) + 4 * c) = o;
  }
}

// ---------------- MFMA semantic scores: scores[r] = tanh(z_r @ W1 + b1) @ w2 ----------------
// rows r in [0, NN*NP), z flattened [300K][128] bf16; one wave per 16-row tile.
__global__ __launch_bounds__(256) void sem_mfma_kernel(
    const unsigned short* __restrict__ zb, const unsigned short* __restrict__ W1T,
    const float* __restrict__ b1, const float* __restrict__ w2,
    float* __restrict__ scores) {
  const int wid = threadIdx.x >> 6, lane = threadIdx.x & 63;
  const int tile = blockIdx.x * 4 + wid;
  if (tile >= (NN * NP) / 16) return;
  const int c = lane & 15, q = lane >> 4;
  f32x4 acc[4];
#pragma unroll
  for (int t = 0; t < 4; ++t) acc[t] = (f32x4){0.f, 0.f, 0.f, 0.f};

  const unsigned short* arow = zb + (size_t)(tile * 16 + c) * 128 + q * 8;
  const unsigned short* brow = W1T + (size_t)c * 128 + q * 8;
#pragma unroll
  for (int kc = 0; kc < 4; ++kc) {
    short8 a = *(const short8*)(arow + kc * 32);
#pragma unroll
    for (int t = 0; t < 4; ++t) {
      short8 b = *(const short8*)(brow + (size_t)t * 16 * 128 + kc * 32);
      acc[t] = __builtin_amdgcn_mfma_f32_16x16x32_bf16(a, b, acc[t], 0, 0, 0);
    }
  }
  // epilogue: tanh + dot w2, reduce over 64 cols (16 lanes x 4 tiles)
  float part[4] = {0.f, 0.f, 0.f, 0.f};   // per row i = q*4+i
#pragma unroll
  for (int t = 0; t < 4; ++t) {
    float bb = b1[t * 16 + c], ww = w2[t * 16 + c];
#pragma unroll
    for (int i = 0; i < 4; ++i) part[i] += tanh_fast(acc[t][i] + bb) * ww;
  }
#pragma unroll
  for (int m = 1; m <= 8; m <<= 1)
#pragma unroll
    for (int i = 0; i < 4; ++i) part[i] += __shfl_xor(part[i], m);
  if (c == 0)
    *(float4*)(scores + (size_t)tile * 16 + q * 4) = make_float4(part[0], part[1], part[2], part[3]);
}

// ---------------- reduce scores into s[3] (p = row % 3) ----------------
__global__ __launch_bounds__(256) void reduce_scores_kernel(
    const float* __restrict__ scores, float* __restrict__ s) {
  __shared__ float red[3][256];
  int t = threadIdx.x;
  float a0 = 0.f, a1 = 0.f, a2 = 0.f;
  for (int i = blockIdx.x * 256 + t; i < NN * NP; i += 256 * 256) {
    float v = scores[i];
    int p = i % 3;
    if (p == 0) a0 += v; else if (p == 1) a1 += v; else a2 += v;
  }
  red[0][t] = a0; red[1][t] = a1; red[2][t] = a2;
  __syncthreads();
  for (int st = 128; st >= 1; st >>= 1) {
    if (t < st) {
      red[0][t] += red[0][t + st];
      red[1][t] += red[1][t + st];
      red[2][t] += red[2][t + st];
    }
    __syncthreads();
  }
  if (t == 0) {
    atomicAdd(&s[0], red[0][0]);
    atomicAdd(&s[1], red[1][0]);
    atomicAdd(&s[2], red[2][0]);
  }
}

// ---------------- beta = softmax(s / N) ----------------
__global__ void beta_kernel(const float* __restrict__ s, float* __restrict__ beta) {
  if (threadIdx.x == 0 && blockIdx.x == 0) {
    float w0 = s[0] / (float)NN, w1 = s[1] / (float)NN, w2 = s[2] / (float)NN;
    float m = fmaxf(w0, fmaxf(w1, w2));
    float e0 = __expf(w0 - m), e1 = __expf(w1 - m), e2 = __expf(w2 - m);
    float inv = 1.f / (e0 + e1 + e2);
    beta[0] = e0 * inv; beta[1] = e1 * inv; beta[2] = e2 * inv;
  }
}

// ---------------- final combine: out = sum_p beta[p] * z[:,p,:] (bf16 z -> fp32 out) ------
__global__ __launch_bounds__(256) void final_kernel(
    const unsigned short* __restrict__ zb, const float* __restrict__ beta,
    float* __restrict__ out) {
  int i = blockIdx.x * blockDim.x + threadIdx.x;   // NN*16 threads, 8 cols each
  if (i >= NN * 16) return;
  int n = i >> 4, g = i & 15;
  float b0 = beta[0], b1 = beta[1], b2 = beta[2];
  const unsigned short* zr = zb + (size_t)n * (NP * 128) + g * 8;
  ushort4 u0a = *(const ushort4*)(zr);
  ushort4 u0b = *(const ushort4*)(zr + 4);
  ushort4 u1a = *(const ushort4*)(zr + 128);
  ushort4 u1b = *(const ushort4*)(zr + 132);
  ushort4 u2a = *(const ushort4*)(zr + 256);
  ushort4 u2b = *(const ushort4*)(zr + 260);
  float4 oa, ob;
  oa.x = b0 * bf2f(u0a.x) + b1 * bf2f(u1a.x) + b2 * bf2f(u2a.x);
  oa.y = b0 * bf2f(u0a.y) + b1 * bf2f(u1a.y) + b2 * bf2f(u2a.y);
  oa.z = b0 * bf2f(u0a.z) + b1 * bf2f(u1a.z) + b2 * bf2f(u2a.z);
  oa.w = b0 * bf2f(u0a.w) + b1 * bf2f(u1a.w) + b2 * bf2f(u2a.w);
  ob.x = b0 * bf2f(u0b.x) + b1 * bf2f(u1b.x) + b2 * bf2f(u2b.x);
  ob.y = b0 * bf2f(u0b.y) + b1 * bf2f(u1b.y) + b2 * bf2f(u2b.y);
  ob.z = b0 * bf2f(u0b.z) + b1 * bf2f(u1b.z) + b2 * bf2f(u2b.z);
  ob.w = b0 * bf2f(u0b.w) + b1 * bf2f(u1b.w) + b2 * bf2f(u2b.w);
  float* op = out + (size_t)n * 128 + g * 8;
  *(float4*)op = oa;
  *(float4*)(op + 4) = ob;
}

// ---------------- init: zero counters + score accumulators ----------------
__global__ __launch_bounds__(256) void zero_kernel(int* __restrict__ cnt, float* __restrict__ s) {
  int i = blockIdx.x * blockDim.x + threadIdx.x;
  if (i < NP * NN) cnt[i] = 0;
  if (i < NP) s[i] = 0.f;
}

extern "C" void kernel_launch(void* const* d_in, const int* in_sizes, int n_in,
                              void* d_out, int out_size, void* d_ws, size_t ws_size,
                              hipStream_t stream) {
  const float* h    = (const float*)d_in[0];
  const int*   esrc = (const int*)d_in[1];
  const int*   edst = (const int*)d_in[2];
  const float* W    = (const float*)d_in[3];
  const float* al   = (const float*)d_in[4];
  const float* ar   = (const float*)d_in[5];
  const float* bias = (const float*)d_in[6];
  const float* w1   = (const float*)d_in[7];
  const float* b1   = (const float*)d_in[8];
  const float* w2   = (const float*)d_in[9];
  float* out = (float*)d_out;

  // workspace layout, ~153 MiB total
  unsigned short* zb    = (unsigned short*)d_ws;           // NN*NP*128 bf16
  unsigned short* featb = zb + (size_t)NN * NP * 128;      // NN*128 bf16
  unsigned short* hb    = featb + (size_t)NN * 128;        // NN*128 bf16
  unsigned short* WT    = hb + (size_t)NN * 128;           // 3*128*128 bf16
  unsigned short* W1T   = WT + NP * 128 * 128;             // 64*128 bf16
  float* el     = (float*)(W1T + NHID * 128);              // NN*4
  float* er     = el + (size_t)NN * NH;                    // NN*4
  float* scores = er + (size_t)NN * NH;                    // NN*NP
  float* s      = scores + (size_t)NN * NP;                // 16 (padded)
  float* beta   = s + 16;                                  // 16 (padded)
  int*   cnt    = (int*)(beta + 16);                       // NP*NN
  int*   elist  = cnt + (size_t)NP * NN;                   // NN*CAP (reused per path)

  zero_kernel<<<(NP * NN + 255) / 256, 256, 0, stream>>>(cnt, s);
  cast_h_kernel<<<(NN * 32 + 255) / 256, 256, 0, stream>>>(h, hb);
  prep_w_kernel<<<(NP * 128 * 128 + NHID * 128 + 255) / 256, 256, 0, stream>>>(W, w1, WT, W1T);

  for (int p = 0; p < NP; ++p) {
    gemm_feat_mfma_kernel<<<(NN / 16 + 3) / 4, 256, 0, stream>>>(
        hb, WT + (size_t)p * 128 * 128, al + p * 128, ar + p * 128, featb, el, er);
    fill_kernel<<<(NE + 255) / 256, 256, 0, stream>>>(esrc + (size_t)p * NE, edst + (size_t)p * NE,
                                                      cnt + (size_t)p * NN, elist);
    gather_kernel<<<NN / 4, 256, 0, stream>>>(featb, el, er, cnt + (size_t)p * NN, elist,
                                              bias + p * 128, zb + p * 128);
  }

  sem_mfma_kernel<<<((NN * NP) / 16 + 3) / 4, 256, 0, stream>>>(zb, W1T, b1, w2, scores);
  reduce_scores_kernel<<<256, 256, 0, stream>>>(scores, s);
  beta_kernel<<<1, 64, 0, stream>>>(s, beta);
  final_kernel<<<(NN * 16 + 255) / 256, 256, 0, stream>>>(zb, beta, out);
}

// Round 4
// 560.261 us; speedup vs baseline: 1.6408x; 1.1098x over previous
//
#include <hip/hip_runtime.h>
#include <hip/hip_bf16.h>
#include <math.h>

// Problem constants (from reference)
#define NN 100000      // nodes
#define NP 3           // metapaths
#define NE 800000      // edges per path
#define NH 4           // heads
#define ND 32          // dim per head
#define HD 128         // H*D
#define NHID 64        // semantic hidden
#define CAP 48         // per-node in-edge cap (Poisson(8): P(deg>=48) ~ 1e-25)
#define XSTR 49        // padded stride for LDS x table (breaks 4-way bank alias)

typedef __attribute__((ext_vector_type(8))) short short8;
typedef __attribute__((ext_vector_type(4))) float f32x4;

__device__ __forceinline__ unsigned short f2bf(float f) {
  union { float f; unsigned int u; } v; v.f = f;
  unsigned int r = v.u + 0x7FFFu + ((v.u >> 16) & 1u);   // round-to-nearest-even
  return (unsigned short)(r >> 16);
}
__device__ __forceinline__ float bf2f(unsigned short u) {
  return __uint_as_float(((unsigned int)u) << 16);
}
__device__ __forceinline__ float tanh_fast(float x) {
  return 1.f - 2.f / (1.f + __expf(2.f * x));   // saturates correctly
}

// ---------------- prep: zero cnt/s + cast h -> bf16 + transpose/cast W, W1 ----------------
__global__ __launch_bounds__(256) void prep_kernel(
    const float* __restrict__ h, const float* __restrict__ W, const float* __restrict__ W1,
    unsigned short* __restrict__ hb, unsigned short* __restrict__ WT,
    unsigned short* __restrict__ W1T, int* __restrict__ cnt, float* __restrict__ s) {
  int i = blockIdx.x * blockDim.x + threadIdx.x;
  if (i < NN * 32) {                       // cast h, 4 elems per thread
    float4 v = ((const float4*)h)[i];
    ushort4 o;
    o.x = f2bf(v.x); o.y = f2bf(v.y); o.z = f2bf(v.z); o.w = f2bf(v.w);
    ((ushort4*)hb)[i] = o;
  }
  if (i < NP * 128 * 128) {                // WT[p][n][k] = W[p][k][n]
    int p = i >> 14, r = i & 16383, n = r >> 7, k = r & 127;
    WT[i] = f2bf(W[(size_t)p * 16384 + k * 128 + n]);
  }
  if (i < NHID * 128) {                    // W1T[n][k] = W1[k][n]
    int n = i >> 7, k = i & 127;
    W1T[i] = f2bf(W1[(size_t)k * NHID + n]);
  }
  if (i < NP * NN) cnt[i] = 0;
  if (i < 4) s[i] = 0.f;
}

// ---------------- MFMA feature GEMM (all paths) + fused el/er ----------------
// grid (NN/64, NP); block 256 = 4 waves; each wave one 16-row tile; WT[p] staged in LDS.
// A-frag: lane holds hb[row=tile*16+c][kc*32 + q*8 .. +7]; B-frag from LDS same layout.
// C/D: col=lane&15, row=q*4+reg  [validated rounds 2-3]
__global__ __launch_bounds__(256) void gemm_mfma_kernel(
    const unsigned short* __restrict__ hb, const unsigned short* __restrict__ WT_all,
    const float* __restrict__ al_all, const float* __restrict__ ar_all,
    unsigned short* __restrict__ featb_all, float* __restrict__ el_all,
    float* __restrict__ er_all) {
  __shared__ unsigned short Bs[128 * 128];   // 32 KB: whole WT[p]
  const int p = blockIdx.y;
  const unsigned short* WTp = WT_all + (size_t)p * 16384;
#pragma unroll
  for (int it = 0; it < 8; ++it)
    ((float4*)Bs)[it * 256 + threadIdx.x] = ((const float4*)WTp)[it * 256 + threadIdx.x];
  __syncthreads();

  const int wid = threadIdx.x >> 6, lane = threadIdx.x & 63;
  const int c = lane & 15, q = lane >> 4;
  const int tile = blockIdx.x * 4 + wid;       // 16-row tile; NN/16 = 6250 exact
  const int tc = tile < 6250 ? tile : 6249;    // clamp for safe loads; stores guarded

  f32x4 acc[8];
#pragma unroll
  for (int t = 0; t < 8; ++t) acc[t] = (f32x4){0.f, 0.f, 0.f, 0.f};

  const unsigned short* arow = hb + (size_t)(tc * 16 + c) * 128 + q * 8;
#pragma unroll
  for (int kc = 0; kc < 4; ++kc) {
    short8 a = *(const short8*)(arow + kc * 32);
#pragma unroll
    for (int t = 0; t < 8; ++t) {
      short8 b = *(const short8*)(Bs + (size_t)(t * 16 + c) * 128 + kc * 32 + q * 8);
      acc[t] = __builtin_amdgcn_mfma_f32_16x16x32_bf16(a, b, acc[t], 0, 0, 0);
    }
  }
  if (tile >= 6250) return;

  unsigned short* featb = featb_all + (size_t)p * NN * 128;
#pragma unroll
  for (int t = 0; t < 8; ++t)
#pragma unroll
    for (int i = 0; i < 4; ++i)
      featb[(size_t)(tc * 16 + q * 4 + i) * 128 + t * 16 + c] = f2bf(acc[t][i]);

  const float* al = al_all + p * 128;
  const float* ar = ar_all + p * 128;
  float alv[8], arv[8];
#pragma unroll
  for (int t = 0; t < 8; ++t) { alv[t] = al[t * 16 + c]; arv[t] = ar[t * 16 + c]; }
  float elp[4][4], erp[4][4];   // [i][hh]
#pragma unroll
  for (int i = 0; i < 4; ++i)
#pragma unroll
    for (int hh = 0; hh < 4; ++hh) {
      elp[i][hh] = acc[2 * hh][i] * alv[2 * hh] + acc[2 * hh + 1][i] * alv[2 * hh + 1];
      erp[i][hh] = acc[2 * hh][i] * arv[2 * hh] + acc[2 * hh + 1][i] * arv[2 * hh + 1];
    }
#pragma unroll
  for (int m = 1; m <= 8; m <<= 1)
#pragma unroll
    for (int i = 0; i < 4; ++i)
#pragma unroll
      for (int hh = 0; hh < 4; ++hh) {
        elp[i][hh] += __shfl_xor(elp[i][hh], m);
        erp[i][hh] += __shfl_xor(erp[i][hh], m);
      }
  if (c == 0) {
    float* el = el_all + (size_t)p * NN * 4;
    float* er = er_all + (size_t)p * NN * 4;
#pragma unroll
    for (int i = 0; i < 4; ++i) {
      int row = tc * 16 + q * 4 + i;
      *(float4*)(el + (size_t)row * 4) = make_float4(elp[i][0], elp[i][1], elp[i][2], elp[i][3]);
      *(float4*)(er + (size_t)row * 4) = make_float4(erp[i][0], erp[i][1], erp[i][2], erp[i][3]);
    }
  }
}

// ---------------- bucket fill (all paths): capped per-dst in-edge lists ----------------
__global__ __launch_bounds__(256) void fill_kernel(
    const int* __restrict__ src_all, const int* __restrict__ dst_all,
    int* __restrict__ cnt_all, int* __restrict__ elist_all) {
  int e = blockIdx.x * blockDim.x + threadIdx.x;
  if (e >= NE) return;
  const int p = blockIdx.y;
  int d = dst_all[(size_t)p * NE + e];
  int pos = atomicAdd(&cnt_all[(size_t)p * NN + d], 1);
  if (pos < CAP) elist_all[((size_t)p * NN + d) * CAP + pos] = src_all[(size_t)p * NE + e];
}

// ---------------- gather (all paths): one wave per (node,path) -------------------------
// Deferred normalization: out = (sum_j x_j*feat_j)/(sum_j x_j); x_j = exp(leaky(el+er)).
__global__ __launch_bounds__(256) void gather_kernel(
    const unsigned short* __restrict__ featb_all, const float* __restrict__ el_all,
    const float* __restrict__ er_all, const int* __restrict__ cnt_all,
    const int* __restrict__ elist_all, const float* __restrict__ bias_all,
    unsigned short* __restrict__ zb) {
  __shared__ int   s_src[4][CAP];
  __shared__ float s_x[4][4 * XSTR];
  const int p = blockIdx.y;
  const unsigned short* featb = featb_all + (size_t)p * NN * 128;
  const float* el = el_all + (size_t)p * NN * 4;
  const int* elist = elist_all + (size_t)p * NN * CAP;
  const int wid = threadIdx.x >> 6;
  const int lane = threadIdx.x & 63;
  const int n = blockIdx.x * 4 + wid;        // NN % 4 == 0
  int deg = cnt_all[(size_t)p * NN + n]; deg = deg > CAP ? CAP : deg;
  float4 ern = *(const float4*)(er_all + (size_t)p * NN * 4 + (size_t)n * 4);

  // pass 1: lane j computes x for edge j (deg <= 48); no shuffle reduction needed.
  float x0 = 0.f, x1 = 0.f, x2 = 0.f, x3 = 0.f;
  int s = 0;
  if (lane < deg) {
    s = elist[(size_t)n * CAP + lane];
    float4 ev = *(const float4*)(el + (size_t)s * 4);
    float e0 = ev.x + ern.x; e0 = fmaxf(e0, 0.2f * e0); x0 = __expf(e0);
    float e1 = ev.y + ern.y; e1 = fmaxf(e1, 0.2f * e1); x1 = __expf(e1);
    float e2 = ev.z + ern.z; e2 = fmaxf(e2, 0.2f * e2); x2 = __expf(e2);
    float e3 = ev.w + ern.w; e3 = fmaxf(e3, 0.2f * e3); x3 = __expf(e3);
  }
  if (lane < CAP) {
    s_src[wid][lane] = s;                  // 0 for lane >= deg (row 0 load, x=0)
    s_x[wid][0 * XSTR + lane] = x0;
    s_x[wid][1 * XSTR + lane] = x1;
    s_x[wid][2 * XSTR + lane] = x2;
    s_x[wid][3 * XSTR + lane] = x3;
  }
  __syncthreads();

  // pass 2: quarter-wave per edge, 4 edges/iter, 16B/lane feat loads.
  const int sub = lane >> 4, c16 = lane & 15;
  const int hh = c16 >> 2;                 // 8 cols/lane -> head = c16/4... cols c16*8..+7, head = (c16*8)/32
  const int* srcs = s_src[wid];
  const float* xs = &s_x[wid][hh * XSTR];
  float acc[8] = {0.f, 0.f, 0.f, 0.f, 0.f, 0.f, 0.f, 0.f};
  float d = 0.f;
  int deg4 = (deg + 3) & ~3;
  for (int i = 0; i < deg4; i += 4) {
    int j = i + sub;
    int sj = srcs[j];
    float xv = xs[j];
    short8 f = *(const short8*)(featb + (size_t)sj * 128 + c16 * 8);
    d += xv;
#pragma unroll
    for (int k = 0; k < 8; ++k) acc[k] += xv * bf2f((unsigned short)f[k]);
  }
  // reduce over the 4 sub-groups (lane bits 4,5)
  d += __shfl_xor(d, 16); d += __shfl_xor(d, 32);
#pragma unroll
  for (int k = 0; k < 8; ++k) {
    acc[k] += __shfl_xor(acc[k], 16);
    acc[k] += __shfl_xor(acc[k], 32);
  }
  if (sub == 0) {
    float rd = d > 0.f ? 1.f / d : 0.f;
    const float* bias = bias_all + p * 128 + c16 * 8;
    float4 b0 = *(const float4*)(bias);
    float4 b1 = *(const float4*)(bias + 4);
    short8 o;
    o[0] = f2bf(acc[0] * rd + b0.x); o[1] = f2bf(acc[1] * rd + b0.y);
    o[2] = f2bf(acc[2] * rd + b0.z); o[3] = f2bf(acc[3] * rd + b0.w);
    o[4] = f2bf(acc[4] * rd + b1.x); o[5] = f2bf(acc[5] * rd + b1.y);
    o[6] = f2bf(acc[6] * rd + b1.z); o[7] = f2bf(acc[7] * rd + b1.w);
    *(short8*)(zb + (size_t)n * (NP * 128) + p * 128 + c16 * 8) = o;
  }
}

// ---------------- MFMA semantic scores, reduced in-kernel to s[3] ----------------
// rows r in [0, NN*NP) of zb ([300K][128] bf16), p = r % 3; one wave per 16-row tile.
__global__ __launch_bounds__(256) void sem_mfma_kernel(
    const unsigned short* __restrict__ zb, const unsigned short* __restrict__ W1T,
    const float* __restrict__ b1, const float* __restrict__ w2,
    float* __restrict__ s) {
  __shared__ float red3[3];
  if (threadIdx.x < 3) red3[threadIdx.x] = 0.f;
  __syncthreads();
  const int wid = threadIdx.x >> 6, lane = threadIdx.x & 63;
  const int tile = blockIdx.x * 4 + wid;       // (NN*NP)/16 = 18750 exact
  const bool active = tile < 18750;
  const int tc = active ? tile : 18749;
  const int c = lane & 15, q = lane >> 4;
  f32x4 acc[4];
#pragma unroll
  for (int t = 0; t < 4; ++t) acc[t] = (f32x4){0.f, 0.f, 0.f, 0.f};

  const unsigned short* arow = zb + (size_t)(tc * 16 + c) * 128 + q * 8;
  const unsigned short* brow = W1T + (size_t)c * 128 + q * 8;
#pragma unroll
  for (int kc = 0; kc < 4; ++kc) {
    short8 a = *(const short8*)(arow + kc * 32);
#pragma unroll
    for (int t = 0; t < 4; ++t) {
      short8 b = *(const short8*)(brow + (size_t)t * 16 * 128 + kc * 32);
      acc[t] = __builtin_amdgcn_mfma_f32_16x16x32_bf16(a, b, acc[t], 0, 0, 0);
    }
  }
  float part[4] = {0.f, 0.f, 0.f, 0.f};
#pragma unroll
  for (int t = 0; t < 4; ++t) {
    float bb = b1[t * 16 + c], ww = w2[t * 16 + c];
#pragma unroll
    for (int i = 0; i < 4; ++i) part[i] += tanh_fast(acc[t][i] + bb) * ww;
  }
#pragma unroll
  for (int m = 1; m <= 8; m <<= 1)
#pragma unroll
    for (int i = 0; i < 4; ++i) part[i] += __shfl_xor(part[i], m);
  if (active && c == 0) {
#pragma unroll
    for (int i = 0; i < 4; ++i)
      atomicAdd(&red3[(tc * 16 + q * 4 + i) % 3], part[i]);
  }
  __syncthreads();
  if (threadIdx.x < 3) atomicAdd(&s[threadIdx.x], red3[threadIdx.x]);
}

// ---------------- beta = softmax(s / N) ----------------
__global__ void beta_kernel(const float* __restrict__ s, float* __restrict__ beta) {
  if (threadIdx.x == 0 && blockIdx.x == 0) {
    float w0 = s[0] / (float)NN, w1 = s[1] / (float)NN, w2 = s[2] / (float)NN;
    float m = fmaxf(w0, fmaxf(w1, w2));
    float e0 = __expf(w0 - m), e1 = __expf(w1 - m), e2 = __expf(w2 - m);
    float inv = 1.f / (e0 + e1 + e2);
    beta[0] = e0 * inv; beta[1] = e1 * inv; beta[2] = e2 * inv;
  }
}

// ---------------- final combine: out = sum_p beta[p] * z[:,p,:] (bf16 z -> fp32 out) ------
__global__ __launch_bounds__(256) void final_kernel(
    const unsigned short* __restrict__ zb, const float* __restrict__ beta,
    float* __restrict__ out) {
  int i = blockIdx.x * blockDim.x + threadIdx.x;   // NN*16 threads, 8 cols each
  if (i >= NN * 16) return;
  int n = i >> 4, g = i & 15;
  float b0 = beta[0], b1 = beta[1], b2 = beta[2];
  const unsigned short* zr = zb + (size_t)n * (NP * 128) + g * 8;
  ushort4 u0a = *(const ushort4*)(zr);
  ushort4 u0b = *(const ushort4*)(zr + 4);
  ushort4 u1a = *(const ushort4*)(zr + 128);
  ushort4 u1b = *(const ushort4*)(zr + 132);
  ushort4 u2a = *(const ushort4*)(zr + 256);
  ushort4 u2b = *(const ushort4*)(zr + 260);
  float4 oa, ob;
  oa.x = b0 * bf2f(u0a.x) + b1 * bf2f(u1a.x) + b2 * bf2f(u2a.x);
  oa.y = b0 * bf2f(u0a.y) + b1 * bf2f(u1a.y) + b2 * bf2f(u2a.y);
  oa.z = b0 * bf2f(u0a.z) + b1 * bf2f(u1a.z) + b2 * bf2f(u2a.z);
  oa.w = b0 * bf2f(u0a.w) + b1 * bf2f(u1a.w) + b2 * bf2f(u2a.w);
  ob.x = b0 * bf2f(u0b.x) + b1 * bf2f(u1b.x) + b2 * bf2f(u2b.x);
  ob.y = b0 * bf2f(u0b.y) + b1 * bf2f(u1b.y) + b2 * bf2f(u2b.y);
  ob.z = b0 * bf2f(u0b.z) + b1 * bf2f(u1b.z) + b2 * bf2f(u2b.z);
  ob.w = b0 * bf2f(u0b.w) + b1 * bf2f(u1b.w) + b2 * bf2f(u2b.w);
  float* op = out + (size_t)n * 128 + g * 8;
  *(float4*)op = oa;
  *(float4*)(op + 4) = ob;
}

extern "C" void kernel_launch(void* const* d_in, const int* in_sizes, int n_in,
                              void* d_out, int out_size, void* d_ws, size_t ws_size,
                              hipStream_t stream) {
  const float* h    = (const float*)d_in[0];
  const int*   esrc = (const int*)d_in[1];
  const int*   edst = (const int*)d_in[2];
  const float* W    = (const float*)d_in[3];
  const float* al   = (const float*)d_in[4];
  const float* ar   = (const float*)d_in[5];
  const float* bias = (const float*)d_in[6];
  const float* w1   = (const float*)d_in[7];
  const float* b1   = (const float*)d_in[8];
  const float* w2   = (const float*)d_in[9];
  float* out = (float*)d_out;

  // workspace layout (~216 MiB); hb aliases elist (hb dead after gemm, elist written after)
  unsigned short* zb    = (unsigned short*)d_ws;       // 38,400,000 bf16
  unsigned short* featb = zb + (size_t)38400000;       // 38,400,000 bf16 (3 paths)
  unsigned short* WT    = featb + (size_t)38400000;    // 49,152 bf16
  unsigned short* W1T   = WT + 49152;                  // 8,192 bf16
  float* el   = (float*)(W1T + 8192);                  // 3*NN*4
  float* er   = el + (size_t)NP * NN * 4;              // 3*NN*4
  float* s    = er + (size_t)NP * NN * 4;              // 16
  float* beta = s + 16;                                // 16
  int*   cnt   = (int*)(beta + 16);                    // NP*NN
  int*   elist = cnt + (size_t)NP * NN;                // NP*NN*CAP = 57.6 MB
  unsigned short* hb = (unsigned short*)elist;         // alias: 25.6 MB inside elist region

  prep_kernel<<<(NN * 32 + 255) / 256, 256, 0, stream>>>(h, W, w1, hb, WT, W1T, cnt, s);

  dim3 gemmGrid(NN / 64 + 1, NP);                      // 1563 x 3 (tiles clamped in-kernel)
  gemm_mfma_kernel<<<gemmGrid, 256, 0, stream>>>(hb, WT, al, ar, featb, el, er);

  dim3 fillGrid((NE + 255) / 256, NP);
  fill_kernel<<<fillGrid, 256, 0, stream>>>(esrc, edst, cnt, elist);

  dim3 gatherGrid(NN / 4, NP);
  gather_kernel<<<gatherGrid, 256, 0, stream>>>(featb, el, er, cnt, elist, bias, zb);

  sem_mfma_kernel<<<(18750 + 3) / 4, 256, 0, stream>>>(zb, W1T, b1, w2, s);
  beta_kernel<<<1, 64, 0, stream>>>(s, beta);
  final_kernel<<<(NN * 16 + 255) / 256, 256, 0, stream>>>(zb, beta, out);
}